// Round 4
// baseline (636.944 us; speedup 1.0000x reference)
//
#include <hip/hip_runtime.h>
#include <hip/hip_bf16.h>

#define H_DIM 2048
#define E_NUM 8
#define I_DIM 4096
#define TWO_I 8192
#define T_TOK 2048

typedef __bf16 bf16x8 __attribute__((ext_vector_type(8)));
typedef float f32x4 __attribute__((ext_vector_type(4)));

static __device__ __forceinline__ unsigned short f2bs(float x) {
    __hip_bfloat16 h = __float2bfloat16(x);
    return __builtin_bit_cast(unsigned short, h);
}

#define GLL(gsrc, ldst) __builtin_amdgcn_global_load_lds( \
    (const __attribute__((address_space(1))) void*)(gsrc), \
    (__attribute__((address_space(3))) void*)(ldst), 16, 0, 0)

// B-tile swizzle (transposed bf16 [n][k] tiles, 128B rows)
#define BSWZ(n) (((((n) & 7) ^ (((n) >> 2) & 7))) << 4)
// A-tile swizzle: physical k-chunk = logical ^ (row&7); GLL source side permutes chunks
#define A_SRC_CHUNK(lane) ((((lane) & 7) ^ (((lane) >> 3) & 7)) * 8)

static __device__ __forceinline__ bf16x8 bload(
    const unsigned short* __restrict__ Bs, int n, int s, int h) {
    int off = (n * 128 + s * 64 + h * 16) ^ BSWZ(n);
    return *reinterpret_cast<const bf16x8*>((const char*)Bs + off);
}

static __device__ __forceinline__ bf16x8 aload(
    const unsigned short* __restrict__ As, int row, int s, int h) {
    int off = row * 128 + ((s * 64 + h * 16) ^ ((row & 7) << 4));
    return *reinterpret_cast<const bf16x8*>((const char*)As + off);
}

#define MFMA16(a, b, c) __builtin_amdgcn_mfma_f32_16x16x32_bf16(a, b, c, 0, 0, 0)

// ---------------- fused router + convert: one wave per token ----------------
__global__ __launch_bounds__(256) void router_convert_kernel(
    const float* __restrict__ hs, const float* __restrict__ rw,
    float* __restrict__ out_scores, int* __restrict__ eidx,
    unsigned short* __restrict__ xb, unsigned short* __restrict__ xs) {
    int tok = blockIdx.x * 4 + (threadIdx.x >> 6);
    int lane = threadIdx.x & 63;
    const float* row = hs + (size_t)tok * H_DIM;
    float4 v[8];
    float acc[E_NUM];
#pragma unroll
    for (int e = 0; e < E_NUM; e++) acc[e] = 0.f;
#pragma unroll
    for (int i = 0; i < 8; i++) {
        int hb = i * 256 + lane * 4;
        v[i] = *reinterpret_cast<const float4*>(row + hb);
        const float* w0 = rw + (size_t)hb * E_NUM;
#pragma unroll
        for (int e = 0; e < E_NUM; e++) {
            acc[e] += v[i].x * w0[e] + v[i].y * w0[E_NUM + e] +
                      v[i].z * w0[2 * E_NUM + e] + v[i].w * w0[3 * E_NUM + e];
        }
    }
#pragma unroll
    for (int e = 0; e < E_NUM; e++) {
#pragma unroll
        for (int o = 32; o > 0; o >>= 1) acc[e] += __shfl_xor(acc[e], o, 64);
    }
    int best = 0; float bv = acc[0];
#pragma unroll
    for (int e = 1; e < E_NUM; e++) { if (acc[e] > bv) { bv = acc[e]; best = e; } }
    float sc = 1.f / (1.f + expf(-bv));
    if (lane < E_NUM) out_scores[(size_t)lane * T_TOK + tok] = (lane == best) ? sc : 0.f;
    if (lane == 0) eidx[tok] = best;
    unsigned short* xbr = xb + (size_t)tok * H_DIM;
    unsigned short* xsr = xs + (size_t)tok * H_DIM;
#pragma unroll
    for (int i = 0; i < 8; i++) {
        int hb = i * 256 + lane * 4;
        ushort4 b, s4;
        b.x = f2bs(v[i].x); b.y = f2bs(v[i].y); b.z = f2bs(v[i].z); b.w = f2bs(v[i].w);
        s4.x = f2bs(v[i].x * sc); s4.y = f2bs(v[i].y * sc);
        s4.z = f2bs(v[i].z * sc); s4.w = f2bs(v[i].w * sc);
        *reinterpret_cast<ushort4*>(xbr + hb) = b;
        *reinterpret_cast<ushort4*>(xsr + hb) = s4;
    }
}

// ---------------- grouping ----------------
__global__ void group_kernel(const int* __restrict__ eidx, int* __restrict__ perm,
                             int* __restrict__ off) {
    __shared__ int cnt[E_NUM];
    __shared__ int base[E_NUM];
    int t = threadIdx.x;
    if (t < E_NUM) cnt[t] = 0;
    __syncthreads();
    for (int i = t; i < T_TOK; i += 256) atomicAdd(&cnt[eidx[i]], 1);
    __syncthreads();
    if (t == 0) {
        int s = 0;
        for (int e = 0; e < E_NUM; e++) { base[e] = s; off[e] = s; s += cnt[e]; }
        off[E_NUM] = s;
    }
    __syncthreads();
    for (int i = t; i < T_TOK; i += 256) {
        int e = eidx[i];
        int p = atomicAdd(&base[e], 1);
        perm[p] = i;
    }
}

// ---------------- GEMM1: pipelined grouped gate_up + SwiGLU -> hmid ----------------
// 512 thr, BM=256, BN=64(gate)+64(up), BK=64, double-buffered, counted vmcnt.
__global__ __launch_bounds__(512, 2) void gemm1_kernel(
    const unsigned short* __restrict__ xb, const unsigned short* __restrict__ xs,
    const float* __restrict__ gup, const float* __restrict__ sg,
    const float* __restrict__ su, const int* __restrict__ perm,
    const int* __restrict__ off, unsigned short* __restrict__ hmid) {
    int nt = blockIdx.x;
    int g = blockIdx.y >> 3;
    int mt = blockIdx.y & 7;
    int rowbase, ng;
    if (g < E_NUM) { rowbase = off[g]; ng = off[g + 1] - rowbase; }
    else { rowbase = 0; ng = T_TOK; }
    int mstart = mt * 256;
    if (mstart >= ng) return;

    __shared__ unsigned short As[2][256 * 64];   // 64 KB
    __shared__ unsigned short Bgs[2][64 * 64];   // 16 KB
    __shared__ unsigned short Bus[2][64 * 64];   // 16 KB

    int tid = threadIdx.x;
    int wave = tid >> 6, lane = tid & 63;
    int wr = wave >> 1, wc = wave & 1;
    int h = lane >> 4, ln = lane & 15;

    const unsigned short* Abase = (g == E_NUM) ? xb : xs;
    unsigned int aoff[4];
#pragma unroll
    for (int j = 0; j < 4; j++) {
        int r = wave * 32 + j * 8 + (lane >> 3);
        int sr = mstart + r; sr = (sr < ng) ? sr : (ng - 1);
        int tokr = (g < E_NUM) ? perm[rowbase + sr] : sr;
        aoff[j] = (unsigned int)tokr * H_DIM + A_SRC_CHUNK(lane);
    }
    int n0 = nt * 64;
    const float* gbase;
    const float* ubase;
    size_t ldb;
    if (g < E_NUM) {
        gbase = gup + (size_t)g * H_DIM * TWO_I + n0;
        ubase = gbase + I_DIM;
        ldb = TWO_I;
    } else {
        gbase = sg + n0;
        ubase = su + n0;
        ldb = I_DIM;
    }
    // B staging: waves 0-3 stage gate, waves 4-7 stage up
    const float* bsrc = (wave < 4) ? gbase : ubase;
    int bk0 = (wave & 3) * 16 + ((lane >> 4) << 2);
    int bnb = (lane & 15) << 2;
    const float* bp = bsrc + (size_t)bk0 * ldb + bnb;

    f32x4 zero = {0.f, 0.f, 0.f, 0.f};
    f32x4 accg[4][2], accu[4][2];
#pragma unroll
    for (int i = 0; i < 4; i++)
#pragma unroll
        for (int j = 0; j < 2; j++) { accg[i][j] = zero; accu[i][j] = zero; }

    f32x4 q0, q1, q2, q3;
    const int NT = H_DIM / 64;

#define G1_BLOAD(t) { const float* p_ = bp + (size_t)(t) * 64 * ldb; \
        q0 = *reinterpret_cast<const f32x4*>(p_); \
        q1 = *reinterpret_cast<const f32x4*>(p_ + ldb); \
        q2 = *reinterpret_cast<const f32x4*>(p_ + 2 * ldb); \
        q3 = *reinterpret_cast<const f32x4*>(p_ + 3 * ldb); }
#define G1_BWRITE(buf) { char* bdst_ = (char*)((wave < 4) ? &Bgs[buf][0] : &Bus[buf][0]); \
        _Pragma("unroll") \
        for (int i_ = 0; i_ < 4; i_++) { int n_ = bnb + i_; ushort4 o_; \
            o_.x = f2bs(q0[i_]); o_.y = f2bs(q1[i_]); o_.z = f2bs(q2[i_]); o_.w = f2bs(q3[i_]); \
            int ob_ = (n_ * 128 + bk0 * 2) ^ BSWZ(n_); \
            *reinterpret_cast<ushort4*>(bdst_ + ob_) = o_; } }
#define G1_AGLL(t, buf) { _Pragma("unroll") \
        for (int j_ = 0; j_ < 4; j_++) \
            GLL(Abase + aoff[j_] + (t) * 64, &As[buf][(wave * 32 + j_ * 8) * 64]); }

    // prologue
    G1_BLOAD(0);
    G1_AGLL(0, 0);
    asm volatile("s_waitcnt vmcnt(0)" ::: "memory");
    G1_BWRITE(0);
    G1_BLOAD(1);
    asm volatile("s_waitcnt lgkmcnt(0)" ::: "memory");
    __builtin_amdgcn_s_barrier();

    int cur = 0;
    for (int t = 0; t < NT; ++t) {
        int tn1 = (t + 1 < NT) ? t + 1 : NT - 1;
        int tn2 = (t + 2 < NT) ? t + 2 : NT - 1;
        G1_BWRITE(cur ^ 1);          // stage B(t+1) from regs (loaded last iter)
        G1_AGLL(tn1, cur ^ 1);       // 4 GLL in flight
        G1_BLOAD(tn2);               // 4 global loads in flight
#pragma unroll
        for (int s = 0; s < 2; s++) {
            bf16x8 a[4];
#pragma unroll
            for (int i = 0; i < 4; i++)
                a[i] = aload(&As[cur][0], wr * 64 + i * 16 + ln, s, h);
            bf16x8 bg0 = bload(&Bgs[cur][0], wc * 32 + ln, s, h);
            bf16x8 bg1 = bload(&Bgs[cur][0], wc * 32 + 16 + ln, s, h);
            bf16x8 bu0 = bload(&Bus[cur][0], wc * 32 + ln, s, h);
            bf16x8 bu1 = bload(&Bus[cur][0], wc * 32 + 16 + ln, s, h);
            __builtin_amdgcn_s_setprio(1);
#pragma unroll
            for (int i = 0; i < 4; i++) {
                accg[i][0] = MFMA16(a[i], bg0, accg[i][0]);
                accg[i][1] = MFMA16(a[i], bg1, accg[i][1]);
                accu[i][0] = MFMA16(a[i], bu0, accu[i][0]);
                accu[i][1] = MFMA16(a[i], bu1, accu[i][1]);
            }
            __builtin_amdgcn_s_setprio(0);
        }
        asm volatile("s_waitcnt vmcnt(4)" ::: "memory");   // GLL A(t+1) landed; B loads stay in flight
        asm volatile("s_waitcnt lgkmcnt(0)" ::: "memory"); // ds_writes landed
        __builtin_amdgcn_s_barrier();
        cur ^= 1;
    }

    int hbase = (g < E_NUM) ? rowbase : T_TOK;
#pragma unroll
    for (int i = 0; i < 4; i++) {
#pragma unroll
        for (int jj = 0; jj < 2; jj++) {
#pragma unroll
            for (int r = 0; r < 4; r++) {
                int row = wr * 64 + i * 16 + h * 4 + r;
                int sr = mstart + row;
                if (sr < ng) {
                    float gv = accg[i][jj][r], uv = accu[i][jj][r];
                    float hv = gv / (1.f + expf(-gv)) * uv;  // silu(g)*u
                    int col = n0 + wc * 32 + jj * 16 + ln;
                    hmid[(size_t)(hbase + sr) * I_DIM + col] = f2bs(hv);
                }
            }
        }
    }
}

// ---------------- GEMM2: pipelined down proj. ADD=0 shared writes, ADD=1 routed accum
// 512 thr, BM=256, BN=128, BK=64, double-buffered, counted vmcnt.
template <int ADD>
__global__ __launch_bounds__(512, 2) void gemm2_kernel(
    const unsigned short* __restrict__ hmid, const float* __restrict__ dwn,
    const float* __restrict__ sd, const int* __restrict__ perm,
    const int* __restrict__ off, float* __restrict__ out) {
    int nt = blockIdx.x;
    int g, mt, rowbase, ng, hbase;
    if (ADD) {
        g = blockIdx.y >> 3; mt = blockIdx.y & 7;
        rowbase = off[g]; ng = off[g + 1] - rowbase; hbase = rowbase;
    } else {
        g = E_NUM; mt = blockIdx.y; rowbase = 0; ng = T_TOK; hbase = T_TOK;
    }
    int mstart = mt * 256;
    if (mstart >= ng) return;

    __shared__ unsigned short As[2][256 * 64];   // 64 KB
    __shared__ unsigned short Bs[2][128 * 64];   // 32 KB

    int tid = threadIdx.x;
    int wave = tid >> 6, lane = tid & 63;
    int wr = wave >> 1, wc = wave & 1;
    int h = lane >> 4, ln = lane & 15;

    unsigned int aoff[4];
#pragma unroll
    for (int j = 0; j < 4; j++) {
        int r = wave * 32 + j * 8 + (lane >> 3);
        int sr = mstart + r; sr = (sr < ng) ? sr : (ng - 1);
        aoff[j] = (unsigned int)(hbase + sr) * I_DIM + A_SRC_CHUNK(lane);
    }
    int n0 = nt * 128;
    const float* bbase = ADD ? (dwn + (size_t)g * I_DIM * H_DIM + n0) : (sd + n0);
    int bk0 = ((tid >> 5) & 15) * 4;
    int bnb = (tid & 31) * 4;
    const float* bp = bbase + (size_t)bk0 * H_DIM + bnb;

    f32x4 zero = {0.f, 0.f, 0.f, 0.f};
    f32x4 acc[4][4];
#pragma unroll
    for (int i = 0; i < 4; i++)
#pragma unroll
        for (int j = 0; j < 4; j++) acc[i][j] = zero;

    f32x4 q0, q1, q2, q3;
    const int NT = I_DIM / 64;

#define G2_BLOAD(t) { const float* p_ = bp + (size_t)(t) * 64 * H_DIM; \
        q0 = *reinterpret_cast<const f32x4*>(p_); \
        q1 = *reinterpret_cast<const f32x4*>(p_ + H_DIM); \
        q2 = *reinterpret_cast<const f32x4*>(p_ + 2 * H_DIM); \
        q3 = *reinterpret_cast<const f32x4*>(p_ + 3 * H_DIM); }
#define G2_BWRITE(buf) { char* bdst_ = (char*)&Bs[buf][0]; \
        _Pragma("unroll") \
        for (int i_ = 0; i_ < 4; i_++) { int n_ = bnb + i_; ushort4 o_; \
            o_.x = f2bs(q0[i_]); o_.y = f2bs(q1[i_]); o_.z = f2bs(q2[i_]); o_.w = f2bs(q3[i_]); \
            int ob_ = (n_ * 128 + bk0 * 2) ^ BSWZ(n_); \
            *reinterpret_cast<ushort4*>(bdst_ + ob_) = o_; } }
#define G2_AGLL(t, buf) { _Pragma("unroll") \
        for (int j_ = 0; j_ < 4; j_++) \
            GLL(hmid + aoff[j_] + (t) * 64, &As[buf][(wave * 32 + j_ * 8) * 64]); }

    G2_BLOAD(0);
    G2_AGLL(0, 0);
    asm volatile("s_waitcnt vmcnt(0)" ::: "memory");
    G2_BWRITE(0);
    G2_BLOAD(1);
    asm volatile("s_waitcnt lgkmcnt(0)" ::: "memory");
    __builtin_amdgcn_s_barrier();

    int cur = 0;
    for (int t = 0; t < NT; ++t) {
        int tn1 = (t + 1 < NT) ? t + 1 : NT - 1;
        int tn2 = (t + 2 < NT) ? t + 2 : NT - 1;
        G2_BWRITE(cur ^ 1);
        G2_AGLL(tn1, cur ^ 1);
        G2_BLOAD(tn2);
#pragma unroll
        for (int s = 0; s < 2; s++) {
            bf16x8 a[4];
#pragma unroll
            for (int i = 0; i < 4; i++)
                a[i] = aload(&As[cur][0], wr * 64 + i * 16 + ln, s, h);
            bf16x8 b[4];
#pragma unroll
            for (int j = 0; j < 4; j++)
                b[j] = bload(&Bs[cur][0], wc * 64 + j * 16 + ln, s, h);
            __builtin_amdgcn_s_setprio(1);
#pragma unroll
            for (int j = 0; j < 4; j++)
#pragma unroll
                for (int i = 0; i < 4; i++)
                    acc[i][j] = MFMA16(a[i], b[j], acc[i][j]);
            __builtin_amdgcn_s_setprio(0);
        }
        asm volatile("s_waitcnt vmcnt(4)" ::: "memory");
        asm volatile("s_waitcnt lgkmcnt(0)" ::: "memory");
        __builtin_amdgcn_s_barrier();
        cur ^= 1;
    }

#pragma unroll
    for (int i = 0; i < 4; i++) {
#pragma unroll
        for (int j = 0; j < 4; j++) {
#pragma unroll
            for (int r = 0; r < 4; r++) {
                int row = wr * 64 + i * 16 + h * 4 + r;
                int sr = mstart + row;
                if (sr < ng) {
                    int tok = ADD ? perm[rowbase + sr] : sr;
                    int col = n0 + wc * 64 + j * 16 + ln;
                    float v = acc[i][j][r];
                    float* o = out + (size_t)tok * H_DIM + col;
                    if (ADD) *o += v; else *o = v;
                }
            }
        }
    }
}

extern "C" void kernel_launch(void* const* d_in, const int* in_sizes, int n_in,
                              void* d_out, int out_size, void* d_ws, size_t ws_size,
                              hipStream_t stream) {
    (void)in_sizes; (void)n_in; (void)out_size;
    const float* hs  = (const float*)d_in[0];
    const float* rw  = (const float*)d_in[1];
    const float* gup = (const float*)d_in[2];
    const float* dwn = (const float*)d_in[3];
    const float* sg  = (const float*)d_in[4];
    const float* su  = (const float*)d_in[5];
    const float* sd  = (const float*)d_in[6];
    float* out = (float*)d_out;
    float* out_scores = out + (size_t)T_TOK * H_DIM;

    char* w = (char*)d_ws;
    size_t o = 0;
    auto alloc = [&](size_t bytes) {
        void* p = w + o;
        o += (bytes + 255) & ~(size_t)255;
        return p;
    };
    unsigned short* xb   = (unsigned short*)alloc((size_t)T_TOK * H_DIM * 2);
    unsigned short* xs   = (unsigned short*)alloc((size_t)T_TOK * H_DIM * 2);
    unsigned short* hmid = (unsigned short*)alloc((size_t)2 * T_TOK * I_DIM * 2);
    int* eidx    = (int*)alloc(T_TOK * 4);
    int* perm    = (int*)alloc(T_TOK * 4);
    int* off     = (int*)alloc(64 * 4);
    if (ws_size < o) return;  // insufficient workspace

    router_convert_kernel<<<T_TOK / 4, 256, 0, stream>>>(hs, rw, out_scores, eidx, xb, xs);
    group_kernel<<<1, 256, 0, stream>>>(eidx, perm, off);

    gemm1_kernel<<<dim3(I_DIM / 64, 9 * 8), 512, 0, stream>>>(
        xb, xs, gup, sg, su, perm, off, hmid);
    gemm2_kernel<0><<<dim3(H_DIM / 128, 8), 512, 0, stream>>>(hmid, dwn, sd, perm, off, out);
    gemm2_kernel<1><<<dim3(H_DIM / 128, E_NUM * 8), 512, 0, stream>>>(hmid, dwn, sd, perm, off, out);
}